// Round 2
// baseline (2049.387 us; speedup 1.0000x reference)
//
#include <hip/hip_runtime.h>
#include <hip/hip_bf16.h>
#include <math.h>

#define NT 256

using bfp = __hip_bfloat16;

// ---- input indices (setup_inputs order) ----
enum {
  I_LEAF = 0, I_SUB, I_SAW, I_SAB, I_LAW, I_LAB, I_PAW, I_PAB,
  I_SCLS, I_SWQKV, I_SBQKV, I_SWO, I_SBO, I_SLNG, I_SLNB, I_SW1, I_SB1, I_SW2, I_SB2,
  I_PCLS, I_PWQKV, I_PBQKV, I_PWO, I_PBO, I_PLNG, I_PLNB, I_PW1, I_PB1, I_PW2, I_PB2,
  I_CLFW, I_CLFB
};

struct P {
  const void* in[32];
  float* parent_al;  // ws [B][2][128]
  float* vecs;       // ws [B][3][128]  (eth, ip, tcp)
  void*  out;        // [B][2]
  int    B;
};

__device__ __forceinline__ float uplo(unsigned int u) { return __uint_as_float(u << 16); }
__device__ __forceinline__ float uphi(unsigned int u) { return __uint_as_float(u & 0xffff0000u); }

// scalar converting load
__device__ __forceinline__ float TF(bfp v) { return __bfloat162float(v); }
__device__ __forceinline__ float TF(float v) { return v; }

// 8-wide converting load (16B for bf16, 32B for fp32; both 16B-aligned here)
__device__ __forceinline__ void LD8(const bfp* p, float* o) {
  uint4 u = *(const uint4*)p;
  o[0] = uplo(u.x); o[1] = uphi(u.x); o[2] = uplo(u.y); o[3] = uphi(u.y);
  o[4] = uplo(u.z); o[5] = uphi(u.z); o[6] = uplo(u.w); o[7] = uphi(u.w);
}
__device__ __forceinline__ void LD8(const float* p, float* o) {
  float4 a = ((const float4*)p)[0], b = ((const float4*)p)[1];
  o[0] = a.x; o[1] = a.y; o[2] = a.z; o[3] = a.w;
  o[4] = b.x; o[5] = b.y; o[6] = b.z; o[7] = b.w;
}

// dtype sentinel: sA_lng is all-ones.  bf16 pair -> 0x3F803F80, fp32 -> 0x3F800000
__device__ __forceinline__ bool mode_is_bf16(const void* lng) {
  return *(const unsigned int*)lng == 0x3F803F80u;
}

__device__ __forceinline__ float wred(float v) {
#pragma unroll
  for (int o = 32; o > 0; o >>= 1) v += __shfl_down(v, o, 64);
  return v;
}

// in-place LayerNorm over E elements in LDS buf; red = 2-float LDS scratch
template <typename T, int E>
__device__ __forceinline__ void ln_inplace(float* buf, float* red,
                                           const T* __restrict__ g,
                                           const T* __restrict__ b) {
  const int tid = threadIdx.x;
  if (tid < 64) {
    float s = 0.f, s2 = 0.f;
    for (int j = tid; j < E; j += 64) { float x = buf[j]; s += x; s2 += x * x; }
    s = wred(s); s2 = wred(s2);
    if (tid == 0) {
      float m = s / (float)E;
      red[0] = m;
      red[1] = s2 / (float)E - m * m;
    }
  }
  __syncthreads();
  const float m = red[0];
  const float inv = 1.0f / sqrtf(red[1] + 1e-5f);
  for (int e = tid; e < E; e += NT)
    buf[e] = (buf[e] - m) * inv * TF(g[e]) + TF(b[e]);
  __syncthreads();
}

// AttentionAggregator, CLS-output only.
// tok: LDS [S-1][E] fp32 tokens (rows 1..S-1 of xc). cls_g: global [E].
// sm: LDS scratch (>= 2E + 2*S*E + 4*S + E + 4E + 2 floats). outv: LDS [E].
template <typename T, int E, int S>
__device__ void agg_cls(const float* __restrict__ tok,
                        const T* __restrict__ cls_g,
                        const T* __restrict__ Wqkv, const T* __restrict__ bqkv,
                        const T* __restrict__ Wo,   const T* __restrict__ bo,
                        const T* __restrict__ lng,  const T* __restrict__ lnb,
                        const T* __restrict__ W1,   const T* __restrict__ b1,
                        const T* __restrict__ W2,   const T* __restrict__ b2,
                        float* sm, float* outv) {
  const int tid = threadIdx.x;
  constexpr int D = E / 4;                  // head dim (H=4)
  const float scale = (D == 16) ? 0.25f : 0.17677669529663687f;  // 1/sqrt(D)

  float* clsb = sm;                 // E
  float* qv   = sm + E;             // E   (q, later reused as o)
  float* kbuf = sm + 2 * E;         // S*E
  float* vbuf = kbuf + S * E;       // S*E
  float* att  = vbuf + S * E;       // 4*S
  float* hrow = att + 4 * S;        // E
  float* mid  = hrow + E;           // 4*E
  float* red  = mid + 4 * E;        // 2

  for (int e = tid; e < E; e += NT) clsb[e] = TF(cls_g[e]);
  __syncthreads();

  // ---- q for CLS row only (row e of Wqkv) ----
  for (int e = tid; e < E; e += NT) {
    const T* w = Wqkv + (size_t)e * E;
    float acc = TF(bqkv[e]);
    for (int j = 0; j < E / 8; ++j) {
      float wv[8];
      LD8(w + 8 * j, wv);
      float4 a = ((const float4*)clsb)[2 * j], c = ((const float4*)clsb)[2 * j + 1];
      acc += a.x * wv[0] + a.y * wv[1] + a.z * wv[2] + a.w * wv[3]
           + c.x * wv[4] + c.y * wv[5] + c.z * wv[6] + c.w * wv[7];
    }
    qv[e] = acc;
  }

  // ---- K and V for all S rows; weight row cached in registers across s ----
  for (int idx = tid; idx < 2 * E; idx += NT) {
    const int isv = (idx >= E) ? 1 : 0;
    const int e = idx & (E - 1);
    const int row = (isv ? 2 * E : E) + e;
    const T* w = Wqkv + (size_t)row * E;
    float acc[S];
    const float bias = TF(bqkv[row]);
#pragma unroll
    for (int s = 0; s < S; ++s) acc[s] = bias;
    for (int j = 0; j < E / 8; ++j) {
      float wv[8];
      LD8(w + 8 * j, wv);
#pragma unroll
      for (int s = 0; s < S; ++s) {
        const float* xr = (s == 0) ? clsb : (tok + (size_t)(s - 1) * E);
        float4 a = ((const float4*)xr)[2 * j];
        float4 c = ((const float4*)xr)[2 * j + 1];
        acc[s] += a.x * wv[0] + a.y * wv[1] + a.z * wv[2] + a.w * wv[3]
                + c.x * wv[4] + c.y * wv[5] + c.z * wv[6] + c.w * wv[7];
      }
    }
    float* dst = isv ? vbuf : kbuf;
#pragma unroll
    for (int s = 0; s < S; ++s) dst[s * E + e] = acc[s];
  }
  __syncthreads();

  // ---- attention scores + softmax (CLS query only) ----
  for (int idx = tid; idx < 4 * S; idx += NT) {
    int h = idx / S, s = idx % S;
    float acc = 0.f;
#pragma unroll
    for (int t = 0; t < D; ++t) acc += qv[h * D + t] * kbuf[s * E + h * D + t];
    att[idx] = acc * scale;
  }
  __syncthreads();
  if (tid < 4) {
    float mx = -1e30f;
#pragma unroll
    for (int s = 0; s < S; ++s) mx = fmaxf(mx, att[tid * S + s]);
    float sum = 0.f;
#pragma unroll
    for (int s = 0; s < S; ++s) {
      float ex = expf(att[tid * S + s] - mx);
      att[tid * S + s] = ex;
      sum += ex;
    }
    float inv = 1.0f / sum;
#pragma unroll
    for (int s = 0; s < S; ++s) att[tid * S + s] *= inv;
  }
  __syncthreads();

  // ---- o = att @ V  (overwrite qv; q is dead) ----
  for (int e = tid; e < E; e += NT) {
    int h = e / D;
    float acc = 0.f;
#pragma unroll
    for (int s = 0; s < S; ++s) acc += att[h * S + s] * vbuf[s * E + e];
    qv[e] = acc;
  }
  __syncthreads();

  // ---- o @ Wo^T + bo + cls residual -> hrow; LN1 ----
  for (int e = tid; e < E; e += NT) {
    const T* w = Wo + (size_t)e * E;
    float acc = TF(bo[e]);
    for (int j = 0; j < E / 8; ++j) {
      float wv[8];
      LD8(w + 8 * j, wv);
      float4 a = ((const float4*)qv)[2 * j], c = ((const float4*)qv)[2 * j + 1];
      acc += a.x * wv[0] + a.y * wv[1] + a.z * wv[2] + a.w * wv[3]
           + c.x * wv[4] + c.y * wv[5] + c.z * wv[6] + c.w * wv[7];
    }
    hrow[e] = acc + clsb[e];
  }
  __syncthreads();
  ln_inplace<T, E>(hrow, red, lng, lnb);

  // ---- FFN: mid = gelu(h @ W1 + b1)  (W1 is [E][4E], coalesced across threads) ----
  for (int m = tid; m < 4 * E; m += NT) {
    float acc = TF(b1[m]);
    for (int j = 0; j < E; ++j) acc += hrow[j] * TF(W1[(size_t)j * 4 * E + m]);
    mid[m] = 0.5f * acc * (1.0f + erff(acc * 0.70710678118654752f));
  }
  __syncthreads();
  // ---- f @ W2 + b2 + residual; LN2 ----
  for (int e = tid; e < E; e += NT) {
    float acc = TF(b2[e]);
    for (int m = 0; m < 4 * E; ++m) acc += mid[m] * TF(W2[(size_t)m * E + e]);
    outv[e] = hrow[e] + acc;
  }
  __syncthreads();
  ln_inplace<T, E>(outv, red, lng, lnb);
}

// ===================== kernel 1: sub path =====================
template <typename T>
__global__ __launch_bounds__(NT) void k_sub(P p) {
  if (mode_is_bf16(p.in[I_SLNG]) != (sizeof(T) == 2)) return;
  __shared__ __align__(16) float feats[11 * 32];
  __shared__ __align__(16) float subal[11 * 64];
  __shared__ __align__(16) float scratch[1664];  // >= 1638
  __shared__ __align__(16) float tcpf[64];
  __shared__ __align__(16) float ipf[64];
  const int tid = threadIdx.x;
  const int b = blockIdx.x;

  const T* sf = (const T*)p.in[I_SUB] + (size_t)b * 11 * 32;
  for (int i = tid; i < 11 * 32; i += NT) feats[i] = TF(sf[i]);
  __syncthreads();

  const T* saW = (const T*)p.in[I_SAW];
  const T* sab = (const T*)p.in[I_SAB];
  for (int idx = tid; idx < 11 * 64; idx += NT) {
    int s = idx >> 6, e = idx & 63;
    float acc = TF(sab[idx]);
    const T* w = saW + (size_t)s * 32 * 64 + e;
#pragma unroll
    for (int d = 0; d < 32; ++d) acc += feats[s * 32 + d] * TF(w[d * 64]);
    subal[idx] = acc;
  }
  __syncthreads();

  const T* SW = (const T*)p.in[I_SWQKV];
  agg_cls<T, 64, 9>(subal, (const T*)p.in[I_SCLS],
                    SW, (const T*)p.in[I_SBQKV],
                    (const T*)p.in[I_SWO], (const T*)p.in[I_SBO],
                    (const T*)p.in[I_SLNG], (const T*)p.in[I_SLNB],
                    (const T*)p.in[I_SW1], (const T*)p.in[I_SB1],
                    (const T*)p.in[I_SW2], (const T*)p.in[I_SB2], scratch, tcpf);
  agg_cls<T, 64, 4>(subal + 8 * 64, (const T*)p.in[I_SCLS] + 64,
                    SW + 192 * 64, (const T*)p.in[I_SBQKV] + 192,
                    (const T*)p.in[I_SWO] + 64 * 64, (const T*)p.in[I_SBO] + 64,
                    (const T*)p.in[I_SLNG] + 64, (const T*)p.in[I_SLNB] + 64,
                    (const T*)p.in[I_SW1] + 64 * 256, (const T*)p.in[I_SB1] + 256,
                    (const T*)p.in[I_SW2] + 256 * 64, (const T*)p.in[I_SB2] + 64,
                    scratch, ipf);

  const T* paW = (const T*)p.in[I_PAW];
  const T* pab = (const T*)p.in[I_PAB];
  for (int idx = tid; idx < 2 * 128; idx += NT) {
    int pi = idx >> 7, e = idx & 127;
    const float* vec = pi ? ipf : tcpf;   // parent_al[:,0]=tcpf@W0, [:,1]=ipf@W1
    float acc = TF(pab[idx]);
    const T* w = paW + (size_t)pi * 64 * 128 + e;
#pragma unroll
    for (int j = 0; j < 64; ++j) acc += vec[j] * TF(w[j * 128]);
    p.parent_al[(size_t)b * 256 + idx] = acc;
  }
}

// ===================== kernel 2: parent aggs (grid.y: 0=eth,1=ip,2=tcp) =====================
template <typename T>
__global__ __launch_bounds__(NT) void k_parent(P p) {
  if (mode_is_bf16(p.in[I_SLNG]) != (sizeof(T) == 2)) return;
  __shared__ __align__(16) float feats[15 * 32];
  __shared__ __align__(16) float tok[16 * 128];
  __shared__ __align__(16) float scratch[5320];  // >= 5318
  __shared__ __align__(16) float outv[128];
  const int tid = threadIdx.x;
  const int b = blockIdx.x;
  const int which = blockIdx.y;
  const int f0 = (which == 0) ? 0 : (which == 1) ? 8 : 19;
  const int nl = (which == 0) ? 8 : (which == 1) ? 11 : 15;
  const int par = (which == 0) ? -1 : (which == 1) ? 1 : 0;

  const T* lf = (const T*)p.in[I_LEAF] + (size_t)b * 34 * 32 + (size_t)f0 * 32;
  for (int i = tid; i < nl * 32; i += NT) feats[i] = TF(lf[i]);
  __syncthreads();

  const T* laW = (const T*)p.in[I_LAW];
  const T* lab = (const T*)p.in[I_LAB];
  for (int idx = tid; idx < nl * 128; idx += NT) {
    int t = idx >> 7, e = idx & 127;
    int f = f0 + t;
    float acc = TF(lab[f * 128 + e]);
    const T* w = laW + (size_t)f * 32 * 128 + e;
#pragma unroll
    for (int d = 0; d < 32; ++d) acc += feats[t * 32 + d] * TF(w[d * 128]);
    tok[idx] = acc;
  }
  if (par >= 0) {
    for (int e = tid; e < 128; e += NT)
      tok[nl * 128 + e] = p.parent_al[(size_t)b * 256 + par * 128 + e];
  }
  __syncthreads();

  const int i = which;
  const T* cls  = (const T*)p.in[I_PCLS] + i * 128;
  const T* Wq   = (const T*)p.in[I_PWQKV] + (size_t)i * 384 * 128;
  const T* bq   = (const T*)p.in[I_PBQKV] + i * 384;
  const T* Wo   = (const T*)p.in[I_PWO] + (size_t)i * 128 * 128;
  const T* bo   = (const T*)p.in[I_PBO] + i * 128;
  const T* lng  = (const T*)p.in[I_PLNG] + i * 128;
  const T* lnb  = (const T*)p.in[I_PLNB] + i * 128;
  const T* W1   = (const T*)p.in[I_PW1] + (size_t)i * 128 * 512;
  const T* b1   = (const T*)p.in[I_PB1] + i * 512;
  const T* W2   = (const T*)p.in[I_PW2] + (size_t)i * 512 * 128;
  const T* b2   = (const T*)p.in[I_PB2] + i * 128;

  if (which == 0)
    agg_cls<T, 128, 9>(tok, cls, Wq, bq, Wo, bo, lng, lnb, W1, b1, W2, b2, scratch, outv);
  else if (which == 1)
    agg_cls<T, 128, 13>(tok, cls, Wq, bq, Wo, bo, lng, lnb, W1, b1, W2, b2, scratch, outv);
  else
    agg_cls<T, 128, 17>(tok, cls, Wq, bq, Wo, bo, lng, lnb, W1, b1, W2, b2, scratch, outv);

  for (int e = tid; e < 128; e += NT)
    p.vecs[(size_t)b * 384 + which * 128 + e] = outv[e];
}

// ===================== kernel 3: pkt agg + classifier =====================
template <typename T>
__global__ __launch_bounds__(NT) void k_pkt(P p) {
  if (mode_is_bf16(p.in[I_SLNG]) != (sizeof(T) == 2)) return;
  __shared__ __align__(16) float tok[3 * 128];
  __shared__ __align__(16) float scratch[1940];  // >= 1938
  __shared__ __align__(16) float outv[128];
  const int tid = threadIdx.x;
  const int b = blockIdx.x;

  for (int i = tid; i < 3 * 128; i += NT) tok[i] = p.vecs[(size_t)b * 384 + i];
  __syncthreads();

  const int i = 3;
  agg_cls<T, 128, 4>(tok, (const T*)p.in[I_PCLS] + i * 128,
                     (const T*)p.in[I_PWQKV] + (size_t)i * 384 * 128,
                     (const T*)p.in[I_PBQKV] + i * 384,
                     (const T*)p.in[I_PWO] + (size_t)i * 128 * 128,
                     (const T*)p.in[I_PBO] + i * 128,
                     (const T*)p.in[I_PLNG] + i * 128, (const T*)p.in[I_PLNB] + i * 128,
                     (const T*)p.in[I_PW1] + (size_t)i * 128 * 512,
                     (const T*)p.in[I_PB1] + i * 512,
                     (const T*)p.in[I_PW2] + (size_t)i * 512 * 128,
                     (const T*)p.in[I_PB2] + i * 128,
                     scratch, outv);

  const T* cw = (const T*)p.in[I_CLFW];
  const T* cb = (const T*)p.in[I_CLFB];
  if (tid < 64) {
    float a0 = 0.f, a1 = 0.f;
    for (int j = tid; j < 128; j += 64) {
      float v = outv[j];
      a0 += v * TF(cw[j * 2]);
      a1 += v * TF(cw[j * 2 + 1]);
    }
    a0 = wred(a0);
    a1 = wred(a1);
    if (tid == 0) {
      float o0 = a0 + TF(cb[0]);
      float o1 = a1 + TF(cb[1]);
      if constexpr (sizeof(T) == 2) {
        ((bfp*)p.out)[(size_t)b * 2]     = __float2bfloat16(o0);
        ((bfp*)p.out)[(size_t)b * 2 + 1] = __float2bfloat16(o1);
      } else {
        ((float*)p.out)[(size_t)b * 2]     = o0;
        ((float*)p.out)[(size_t)b * 2 + 1] = o1;
      }
    }
  }
}

extern "C" void kernel_launch(void* const* d_in, const int* in_sizes, int n_in,
                              void* d_out, int out_size, void* d_ws, size_t ws_size,
                              hipStream_t stream) {
  P p;
  for (int i = 0; i < 32; ++i) p.in[i] = d_in[i];
  const int B = in_sizes[0] / (34 * 32);
  p.B = B;
  float* ws = (float*)d_ws;
  p.parent_al = ws;                        // B*256 floats
  p.vecs = ws + (size_t)B * 256;           // B*384 floats
  p.out = d_out;

  k_sub<bfp><<<dim3(B), dim3(NT), 0, stream>>>(p);
  k_sub<float><<<dim3(B), dim3(NT), 0, stream>>>(p);
  k_parent<bfp><<<dim3(B, 3), dim3(NT), 0, stream>>>(p);
  k_parent<float><<<dim3(B, 3), dim3(NT), 0, stream>>>(p);
  k_pkt<bfp><<<dim3(B), dim3(NT), 0, stream>>>(p);
  k_pkt<float><<<dim3(B), dim3(NT), 0, stream>>>(p);
}

// Round 6
// 1795.626 us; speedup vs baseline: 1.1413x; 1.1413x over previous
//
#include <hip/hip_runtime.h>
#include <hip/hip_bf16.h>
#include <math.h>

#define NT 256

// NOTE (round-5 post-mortem): inputs AND output are fp32, not bf16.
// Evidence: R1 (bf16 reads) NaN'd; R2's sentinel-dispatch passed via its fp32
// branch (absmax 2^-11, fp32 out writes accepted). All pointers here are float.

enum {
  I_LEAF = 0, I_SUB, I_SAW, I_SAB, I_LAW, I_LAB, I_PAW, I_PAB,
  I_SCLS, I_SWQKV, I_SBQKV, I_SWO, I_SBO, I_SLNG, I_SLNB, I_SW1, I_SB1, I_SW2, I_SB2,
  I_PCLS, I_PWQKV, I_PBQKV, I_PWO, I_PBO, I_PLNG, I_PLNB, I_PW1, I_PB1, I_PW2, I_PB2,
  I_CLFW, I_CLFB
};

struct P {
  const float* in[32];
  float* parent_al;  // ws [B][2][128]
  float* vecs;       // ws [B][3][128]  (eth, ip, tcp)
  float* out;        // [B][2]
};

__device__ __forceinline__ void LD8(const float* p, float* o) {
  float4 a = ((const float4*)p)[0], b = ((const float4*)p)[1];
  o[0] = a.x; o[1] = a.y; o[2] = a.z; o[3] = a.w;
  o[4] = b.x; o[5] = b.y; o[6] = b.z; o[7] = b.w;
}

__device__ __forceinline__ float wred(float v) {
#pragma unroll
  for (int o = 32; o > 0; o >>= 1) v += __shfl_down(v, o, 64);
  return v;
}

// in-place LayerNorm over E elements in LDS buf; red = 2-float LDS scratch
template <int E>
__device__ __forceinline__ void ln_inplace(float* buf, float* red,
                                           const float* __restrict__ g,
                                           const float* __restrict__ b) {
  const int tid = threadIdx.x;
  if (tid < 64) {
    float s = 0.f, s2 = 0.f;
    for (int j = tid; j < E; j += 64) { float x = buf[j]; s += x; s2 += x * x; }
    s = wred(s); s2 = wred(s2);
    if (tid == 0) {
      float m = s / (float)E;
      red[0] = m;
      red[1] = s2 / (float)E - m * m;
    }
  }
  __syncthreads();
  const float m = red[0];
  const float inv = 1.0f / sqrtf(red[1] + 1e-5f);
  for (int e = tid; e < E; e += NT)
    buf[e] = (buf[e] - m) * inv * g[e] + b[e];
  __syncthreads();
}

// AttentionAggregator, CLS-output only, K/V folded away:
//   q = Wq.cls + bq ; u_h = scale * Wk_h^T q_h ; sb_h = scale * q_h . bk_h
//   score[h][s] = sb_h + x_s . u_h ; xbar_h = sum_s att * x_s
//   o = Wv . xbar + bv ; then Wo / LN / FFN / LN exactly as the R2 fp32 path.
// tok: LDS [S-1][E] fp32 tokens (rows 1..S-1 of xc). cls_g: global fp32 [E].
// Wqkv/bqkv are the FULL in_proj ([3E,E] / [3E]) for this aggregator.
// sm: LDS scratch >= 16E + 4S + 6 floats. outv: LDS [E].
template <int E, int S>
__device__ void agg_cls(const float* __restrict__ tok,
                        const float* __restrict__ cls_g,
                        const float* __restrict__ Wqkv, const float* __restrict__ bqkv,
                        const float* __restrict__ Wo,   const float* __restrict__ bo,
                        const float* __restrict__ lng,  const float* __restrict__ lnb,
                        const float* __restrict__ W1,   const float* __restrict__ b1,
                        const float* __restrict__ W2,   const float* __restrict__ b2,
                        float* sm, float* outv) {
  const int tid = threadIdx.x;
  constexpr int D = E / 4;                  // head dim (H=4)
  const float scale = (D == 16) ? 0.25f : 0.17677669529663687f;  // 1/sqrt(D)

  float* clsb = sm;                       // E
  float* qb   = sm + E;                   // E
  float* ub   = sm + 2 * E;               // 4E
  float* sb4  = sm + 6 * E;               // 4
  float* att  = sm + 6 * E + 4;           // 4S
  float* xbar = sm + 6 * E + 4 + 4 * S;   // 4E
  float* ov   = sm + 10 * E + 4 + 4 * S;  // E
  float* hrow = sm + 11 * E + 4 + 4 * S;  // E
  float* mid  = sm + 12 * E + 4 + 4 * S;  // 4E
  float* red  = sm + 16 * E + 4 + 4 * S;  // 2

  for (int e = tid; e < E; e += NT) clsb[e] = cls_g[e];
  __syncthreads();

  // ---- q for CLS row only (row e of Wqkv) ----
  for (int e = tid; e < E; e += NT) {
    const float* w = Wqkv + (size_t)e * E;
    float acc = bqkv[e];
    for (int j = 0; j < E / 8; ++j) {
      float wv[8];
      LD8(w + 8 * j, wv);
      float4 a = ((const float4*)clsb)[2 * j], c = ((const float4*)clsb)[2 * j + 1];
      acc += a.x * wv[0] + a.y * wv[1] + a.z * wv[2] + a.w * wv[3]
           + c.x * wv[4] + c.y * wv[5] + c.z * wv[6] + c.w * wv[7];
    }
    qb[e] = acc;
  }
  __syncthreads();

  // ---- u_h[k] = scale * sum_d Wk[h*D+d][k] * q[h*D+d] ; sb_h ----
  for (int i = tid; i < 4 * E; i += NT) {
    int h = i / E, k = i - h * E;
    float acc = 0.f;
    for (int d = 0; d < D; ++d)
      acc += Wqkv[(size_t)(E + h * D + d) * E + k] * qb[h * D + d];
    ub[i] = acc * scale;
  }
  if (tid < 4) {
    float acc = 0.f;
    for (int d = 0; d < D; ++d) acc += qb[tid * D + d] * bqkv[E + tid * D + d];
    sb4[tid] = acc * scale;
  }
  __syncthreads();

  // ---- scores[h][s] = sb_h + x_s . u_h ----
  for (int i = tid; i < 4 * S; i += NT) {
    int h = i / S, s = i - h * S;
    const float* x = (s == 0) ? clsb : (tok + (size_t)(s - 1) * E);
    const float* u = ub + h * E;
    float acc = sb4[h];
    for (int k = 0; k < E; ++k) acc += x[k] * u[k];
    att[i] = acc;
  }
  __syncthreads();

  // ---- softmax ----
  if (tid < 4) {
    float mx = -1e30f;
#pragma unroll
    for (int s = 0; s < S; ++s) mx = fmaxf(mx, att[tid * S + s]);
    float sum = 0.f;
#pragma unroll
    for (int s = 0; s < S; ++s) {
      float ex = expf(att[tid * S + s] - mx);
      att[tid * S + s] = ex;
      sum += ex;
    }
    float inv = 1.0f / sum;
#pragma unroll
    for (int s = 0; s < S; ++s) att[tid * S + s] *= inv;
  }
  __syncthreads();

  // ---- xbar[h][k] = sum_s att[h][s] * x_s[k] ----
  for (int i = tid; i < 4 * E; i += NT) {
    int h = i / E, k = i - h * E;
    const float* a = att + h * S;
    float acc = a[0] * clsb[k];
    for (int s = 1; s < S; ++s) acc += a[s] * tok[(size_t)(s - 1) * E + k];
    xbar[i] = acc;
  }
  __syncthreads();

  // ---- o[e] = bv[e] + Wv[e][:] . xbar[head(e)][:] ----
  {
    const float* Wv = Wqkv + (size_t)2 * E * E;
    const float* bv = bqkv + 2 * E;
    for (int e = tid; e < E; e += NT) {
      const float* w = Wv + (size_t)e * E;
      const float* xb = xbar + (e / D) * E;
      float acc = bv[e];
      for (int j = 0; j < E / 8; ++j) {
        float wv[8];
        LD8(w + 8 * j, wv);
        float4 a = ((const float4*)xb)[2 * j], c = ((const float4*)xb)[2 * j + 1];
        acc += a.x * wv[0] + a.y * wv[1] + a.z * wv[2] + a.w * wv[3]
             + c.x * wv[4] + c.y * wv[5] + c.z * wv[6] + c.w * wv[7];
      }
      ov[e] = acc;
    }
  }
  __syncthreads();

  // ---- h = o @ Wo^T + bo + cls residual; LN1 ----
  for (int e = tid; e < E; e += NT) {
    const float* w = Wo + (size_t)e * E;
    float acc = bo[e];
    for (int j = 0; j < E / 8; ++j) {
      float wv[8];
      LD8(w + 8 * j, wv);
      float4 a = ((const float4*)ov)[2 * j], c = ((const float4*)ov)[2 * j + 1];
      acc += a.x * wv[0] + a.y * wv[1] + a.z * wv[2] + a.w * wv[3]
           + c.x * wv[4] + c.y * wv[5] + c.z * wv[6] + c.w * wv[7];
    }
    hrow[e] = acc + clsb[e];
  }
  __syncthreads();
  ln_inplace<E>(hrow, red, lng, lnb);

  // ---- FFN1: mid = gelu(h @ W1 + b1) ----
  for (int m = tid; m < 4 * E; m += NT) {
    float acc = b1[m];
    for (int j = 0; j < E; ++j) acc += hrow[j] * W1[(size_t)j * 4 * E + m];
    mid[m] = 0.5f * acc * (1.0f + erff(acc * 0.70710678118654752f));
  }
  __syncthreads();
  // ---- FFN2 + residual; LN2 ----
  for (int e = tid; e < E; e += NT) {
    float acc = b2[e];
    for (int m = 0; m < 4 * E; ++m) acc += mid[m] * W2[(size_t)m * E + e];
    outv[e] = hrow[e] + acc;
  }
  __syncthreads();
  ln_inplace<E>(outv, red, lng, lnb);
}

// ===================== kernel 1: sub path =====================
__global__ __launch_bounds__(NT) void k_sub(P p) {
  __shared__ __align__(16) float feats[11 * 32];
  __shared__ __align__(16) float subal[11 * 64];
  __shared__ __align__(16) float scratch[1088];  // >= 16*64+4*9+6 = 1066
  __shared__ __align__(16) float tcpf[64];
  __shared__ __align__(16) float ipf[64];
  const int tid = threadIdx.x;
  const int b = blockIdx.x;

  const float* sf = p.in[I_SUB] + (size_t)b * 11 * 32;
  for (int i = tid; i < 11 * 32; i += NT) feats[i] = sf[i];
  __syncthreads();

  const float* saW = p.in[I_SAW];
  const float* sab = p.in[I_SAB];
  for (int idx = tid; idx < 11 * 64; idx += NT) {
    int s = idx >> 6, e = idx & 63;
    float acc = sab[idx];
    const float* w = saW + (size_t)s * 32 * 64 + e;
#pragma unroll
    for (int d = 0; d < 32; ++d) acc += feats[s * 32 + d] * w[d * 64];
    subal[idx] = acc;
  }
  __syncthreads();

  agg_cls<64, 9>(subal, p.in[I_SCLS],
                 p.in[I_SWQKV], p.in[I_SBQKV],
                 p.in[I_SWO], p.in[I_SBO],
                 p.in[I_SLNG], p.in[I_SLNB],
                 p.in[I_SW1], p.in[I_SB1],
                 p.in[I_SW2], p.in[I_SB2], scratch, tcpf);
  agg_cls<64, 4>(subal + 8 * 64, p.in[I_SCLS] + 64,
                 p.in[I_SWQKV] + 192 * 64, p.in[I_SBQKV] + 192,
                 p.in[I_SWO] + 64 * 64, p.in[I_SBO] + 64,
                 p.in[I_SLNG] + 64, p.in[I_SLNB] + 64,
                 p.in[I_SW1] + 64 * 256, p.in[I_SB1] + 256,
                 p.in[I_SW2] + 256 * 64, p.in[I_SB2] + 64,
                 scratch, ipf);

  const float* paW = p.in[I_PAW];
  const float* pab = p.in[I_PAB];
  for (int idx = tid; idx < 2 * 128; idx += NT) {
    int pi = idx >> 7, e = idx & 127;
    const float* vec = pi ? ipf : tcpf;   // parent_al[:,0]=tcpf@W0, [:,1]=ipf@W1
    float acc = pab[idx];
    const float* w = paW + (size_t)pi * 64 * 128 + e;
#pragma unroll
    for (int j = 0; j < 64; ++j) acc += vec[j] * w[j * 128];
    p.parent_al[(size_t)b * 256 + idx] = acc;
  }
}

// ===================== kernel 2: parent aggs =====================
__global__ __launch_bounds__(NT) void k_parent(P p) {
  __shared__ __align__(16) float feats[15 * 32];
  __shared__ __align__(16) float tok[16 * 128];
  __shared__ __align__(16) float scratch[2176];  // >= 16*128+4*17+6 = 2122
  __shared__ __align__(16) float outv[128];
  const int tid = threadIdx.x;
  const int b = blockIdx.x;
  const int which = blockIdx.y;
  const int f0 = (which == 0) ? 0 : (which == 1) ? 8 : 19;
  const int nl = (which == 0) ? 8 : (which == 1) ? 11 : 15;
  const int par = (which == 0) ? -1 : (which == 1) ? 1 : 0;

  const float* lf = p.in[I_LEAF] + (size_t)b * 34 * 32 + (size_t)f0 * 32;
  for (int i = tid; i < nl * 32; i += NT) feats[i] = lf[i];
  __syncthreads();

  const float* laW = p.in[I_LAW];
  const float* lab = p.in[I_LAB];
  for (int idx = tid; idx < nl * 128; idx += NT) {
    int t = idx >> 7, e = idx & 127;
    int f = f0 + t;
    float acc = lab[f * 128 + e];
    const float* w = laW + (size_t)f * 32 * 128 + e;
#pragma unroll
    for (int d = 0; d < 32; ++d) acc += feats[t * 32 + d] * w[d * 128];
    tok[idx] = acc;
  }
  if (par >= 0) {
    for (int e = tid; e < 128; e += NT)
      tok[nl * 128 + e] = p.parent_al[(size_t)b * 256 + par * 128 + e];
  }
  __syncthreads();

  const int i = which;
  const float* cls  = p.in[I_PCLS] + i * 128;
  const float* Wq   = p.in[I_PWQKV] + (size_t)i * 384 * 128;
  const float* bq   = p.in[I_PBQKV] + i * 384;
  const float* Wo   = p.in[I_PWO] + (size_t)i * 128 * 128;
  const float* bo   = p.in[I_PBO] + i * 128;
  const float* lng  = p.in[I_PLNG] + i * 128;
  const float* lnb  = p.in[I_PLNB] + i * 128;
  const float* W1   = p.in[I_PW1] + (size_t)i * 128 * 512;
  const float* b1   = p.in[I_PB1] + i * 512;
  const float* W2   = p.in[I_PW2] + (size_t)i * 512 * 128;
  const float* b2   = p.in[I_PB2] + i * 128;

  if (which == 0)
    agg_cls<128, 9>(tok, cls, Wq, bq, Wo, bo, lng, lnb, W1, b1, W2, b2, scratch, outv);
  else if (which == 1)
    agg_cls<128, 13>(tok, cls, Wq, bq, Wo, bo, lng, lnb, W1, b1, W2, b2, scratch, outv);
  else
    agg_cls<128, 17>(tok, cls, Wq, bq, Wo, bo, lng, lnb, W1, b1, W2, b2, scratch, outv);

  for (int e = tid; e < 128; e += NT)
    p.vecs[(size_t)b * 384 + which * 128 + e] = outv[e];
}

// ===================== kernel 3: pkt agg + classifier =====================
__global__ __launch_bounds__(NT) void k_pkt(P p) {
  __shared__ __align__(16) float tok[3 * 128];
  __shared__ __align__(16) float scratch[2176];  // >= 16*128+4*4+6 = 2070
  __shared__ __align__(16) float outv[128];
  const int tid = threadIdx.x;
  const int b = blockIdx.x;

  for (int i = tid; i < 3 * 128; i += NT) tok[i] = p.vecs[(size_t)b * 384 + i];
  __syncthreads();

  const int i = 3;
  agg_cls<128, 4>(tok, p.in[I_PCLS] + i * 128,
                  p.in[I_PWQKV] + (size_t)i * 384 * 128, p.in[I_PBQKV] + i * 384,
                  p.in[I_PWO] + (size_t)i * 128 * 128, p.in[I_PBO] + i * 128,
                  p.in[I_PLNG] + i * 128, p.in[I_PLNB] + i * 128,
                  p.in[I_PW1] + (size_t)i * 128 * 512, p.in[I_PB1] + i * 512,
                  p.in[I_PW2] + (size_t)i * 512 * 128, p.in[I_PB2] + i * 128,
                  scratch, outv);

  const float* cw = p.in[I_CLFW];
  const float* cb = p.in[I_CLFB];
  if (tid < 64) {
    float a0 = 0.f, a1 = 0.f;
    for (int j = tid; j < 128; j += 64) {
      float v = outv[j];
      a0 += v * cw[j * 2];
      a1 += v * cw[j * 2 + 1];
    }
    a0 = wred(a0);
    a1 = wred(a1);
    if (tid == 0) {
      p.out[(size_t)b * 2]     = a0 + cb[0];
      p.out[(size_t)b * 2 + 1] = a1 + cb[1];
    }
  }
}

extern "C" void kernel_launch(void* const* d_in, const int* in_sizes, int n_in,
                              void* d_out, int out_size, void* d_ws, size_t ws_size,
                              hipStream_t stream) {
  P p;
  for (int i = 0; i < 32; ++i) p.in[i] = (const float*)d_in[i];
  const int B = in_sizes[0] / (34 * 32);
  float* ws = (float*)d_ws;
  p.parent_al = ws;                        // B*256 floats
  p.vecs = ws + (size_t)B * 256;           // B*384 floats
  p.out = (float*)d_out;

  k_sub<<<dim3(B), dim3(NT), 0, stream>>>(p);
  k_parent<<<dim3(B, 3), dim3(NT), 0, stream>>>(p);
  k_pkt<<<dim3(B), dim3(NT), 0, stream>>>(p);
}

// Round 7
// 1217.877 us; speedup vs baseline: 1.6828x; 1.4744x over previous
//
#include <hip/hip_runtime.h>
#include <math.h>

#define NT 256
#define G 4

// fp32 problem (validated R6). G=4 batches per block: each weight chunk is
// loaded to registers once and feeds G FMAs against LDS-resident activations.

enum {
  I_LEAF = 0, I_SUB, I_SAW, I_SAB, I_LAW, I_LAB, I_PAW, I_PAB,
  I_SCLS, I_SWQKV, I_SBQKV, I_SWO, I_SBO, I_SLNG, I_SLNB, I_SW1, I_SB1, I_SW2, I_SB2,
  I_PCLS, I_PWQKV, I_PBQKV, I_PWO, I_PBO, I_PLNG, I_PLNB, I_PW1, I_PB1, I_PW2, I_PB2,
  I_CLFW, I_CLFB
};

struct P {
  const float* in[32];
  float* parent_al;  // ws [B][2][128]
  float* vecs;       // ws [B][3][128]
  float* out;        // [B][2]
};

__device__ __forceinline__ void LD8(const float* p, float* o) {
  float4 a = ((const float4*)p)[0], b = ((const float4*)p)[1];
  o[0] = a.x; o[1] = a.y; o[2] = a.z; o[3] = a.w;
  o[4] = b.x; o[5] = b.y; o[6] = b.z; o[7] = b.w;
}
__device__ __forceinline__ void fma8(float& acc, const float* x, const float* w) {
#pragma unroll
  for (int i = 0; i < 8; ++i) acc += x[i] * w[i];
}
__device__ __forceinline__ float gelu(float v) {
  return 0.5f * v * (1.0f + erff(v * 0.70710678118654752f));
}

// LayerNorm rows in place: buf [G][E]; one wave per row (G=4 -> one row each).
template <int E>
__device__ void ln_rows(float* buf, const float* __restrict__ gg, const float* __restrict__ bb) {
  const int w = threadIdx.x >> 6, lane = threadIdx.x & 63;
  for (int g = w; g < G; g += 4) {
    float* row = buf + g * E;
    float s = 0.f, s2 = 0.f;
    for (int e = lane; e < E; e += 64) { float x = row[e]; s += x; s2 += x * x; }
#pragma unroll
    for (int off = 1; off < 64; off <<= 1) {
      s += __shfl_xor(s, off, 64);
      s2 += __shfl_xor(s2, off, 64);
    }
    float m = s / (float)E;
    float inv = 1.0f / sqrtf(s2 / (float)E - m * m + 1e-5f);
    for (int e = lane; e < E; e += 64) row[e] = (row[e] - m) * inv * gg[e] + bb[e];
  }
}

// Per-block q/u/sb: q = Wq.cls + bq ; u_h = scale * Wk_h^T q_h ; sb_h = scale * q_h.bk_h
// clsb must be loaded+synced by caller. Ends with __syncthreads().
template <int E>
__device__ void compute_usb(const float* __restrict__ Wq, const float* __restrict__ bq,
                            const float* __restrict__ clsb, float* qb,
                            float* uL, float* sbL) {
  const int tid = threadIdx.x;
  constexpr int D = E / 4;
  const float scale = (D == 16) ? 0.25f : 0.17677669529663687f;
  if (tid < E) {
    float acc = bq[tid];
    const float* w = Wq + (size_t)tid * E;
    for (int k = 0; k < E; k += 8) {
      float wv[8];
      LD8(w + k, wv);
#pragma unroll
      for (int ii = 0; ii < 8; ++ii) acc += clsb[k + ii] * wv[ii];
    }
    qb[tid] = acc;
  }
  __syncthreads();
  if (tid < E) {
    for (int h = 0; h < 4; ++h) {
      float acc = 0.f;
      for (int d = 0; d < D; ++d)
        acc += Wq[(size_t)(E + h * D + d) * E + tid] * qb[h * D + d];
      uL[h * E + tid] = acc * scale;
    }
  }
  if (tid < 4) {
    float acc = 0.f;
    for (int d = 0; d < D; ++d) acc += qb[tid * D + d] * bq[E + tid * D + d];
    sbL[tid] = acc * scale;
  }
  __syncthreads();
}

// Folded CLS-only aggregator over G batches.
// X: fp32 tokens [T][G][E] (rows 1..S-1 of xc). Result fp32 [G][E] in o.
template <int E, int T>
__device__ void agg_run(const float* __restrict__ X, const float* __restrict__ clsb,
                        const float* __restrict__ uL, const float* __restrict__ sbL,
                        const float* __restrict__ Wv, const float* __restrict__ bv,
                        const float* __restrict__ Wo, const float* __restrict__ bo,
                        const float* __restrict__ lng, const float* __restrict__ lnb,
                        const float* __restrict__ W1, const float* __restrict__ b1,
                        const float* __restrict__ W2, const float* __restrict__ b2,
                        float* att, float* xbar, float* o, float* h, float* mid,
                        float* partial) {
  const int tid = threadIdx.x;
  constexpr int S = T + 1, D = E / 4, KS = NT / E, KCH = E / KS;
  constexpr int M1 = (4 * E) / NT, KCH2 = (4 * E) / KS;

  // scores[g][h][s] = sb[h] + x_s . u_h
  for (int i = tid; i < G * 4 * S; i += NT) {
    int s = i % S, hh = (i / S) % 4, g = i / (4 * S);
    const float* u = uL + hh * E;
    const float* x = (s == 0) ? clsb : (X + (size_t)((s - 1) * G + g) * E);
    float acc = sbL[hh];
    for (int k = 0; k < E; k += 8) {
      float xv[8], uv[8];
      LD8(x + k, xv);
      LD8(u + k, uv);
      fma8(acc, xv, uv);
    }
    att[(g * 4 + hh) * S + s] = acc;
  }
  __syncthreads();
  // softmax over s
  for (int i = tid; i < G * 4; i += NT) {
    float* a = att + i * S;
    float mx = a[0];
    for (int s = 1; s < S; ++s) mx = fmaxf(mx, a[s]);
    float sum = 0.f;
    for (int s = 0; s < S; ++s) { float e = expf(a[s] - mx); a[s] = e; sum += e; }
    float inv = 1.0f / sum;
    for (int s = 0; s < S; ++s) a[s] *= inv;
  }
  __syncthreads();
  // xbar[g][h][k] = sum_s att * x_s[k]
  for (int i = tid; i < G * 4 * E; i += NT) {
    int k = i % E, hh = (i / E) % 4, g = i / (4 * E);
    const float* a = att + (g * 4 + hh) * S;
    float acc = a[0] * clsb[k];
    for (int s = 1; s < S; ++s) acc += a[s] * X[(size_t)((s - 1) * G + g) * E + k];
    xbar[i] = acc;
  }
  __syncthreads();
  // o[e] = bv[e] + Wv[e][:] . xbar[head(e)][:]
  {
    const int e = tid % E, ks = tid / E, hh = e / D;
    const float* w = Wv + (size_t)e * E + ks * KCH;
    float acc[G];
#pragma unroll
    for (int g = 0; g < G; ++g) acc[g] = 0.f;
    for (int kc = 0; kc < KCH; kc += 8) {
      float wv[8];
      LD8(w + kc, wv);
#pragma unroll
      for (int g = 0; g < G; ++g) {
        float xv[8];
        LD8(xbar + (g * 4 + hh) * E + ks * KCH + kc, xv);
        fma8(acc[g], xv, wv);
      }
    }
#pragma unroll
    for (int g = 0; g < G; ++g) partial[(ks * G + g) * E + e] = acc[g];
  }
  __syncthreads();
  for (int i = tid; i < G * E; i += NT) {
    int e = i % E, g = i / E;
    float v = bv[e];
#pragma unroll
    for (int ks = 0; ks < KS; ++ks) v += partial[(ks * G + g) * E + e];
    o[g * E + e] = v;
  }
  __syncthreads();
  // h[e] = bo[e] + cls[e] + Wo[e][:] . o[:]
  {
    const int e = tid % E, ks = tid / E;
    const float* w = Wo + (size_t)e * E + ks * KCH;
    float acc[G];
#pragma unroll
    for (int g = 0; g < G; ++g) acc[g] = 0.f;
    for (int kc = 0; kc < KCH; kc += 8) {
      float wv[8];
      LD8(w + kc, wv);
#pragma unroll
      for (int g = 0; g < G; ++g) {
        float xv[8];
        LD8(o + g * E + ks * KCH + kc, xv);
        fma8(acc[g], xv, wv);
      }
    }
#pragma unroll
    for (int g = 0; g < G; ++g) partial[(ks * G + g) * E + e] = acc[g];
  }
  __syncthreads();
  for (int i = tid; i < G * E; i += NT) {
    int e = i % E, g = i / E;
    float v = bo[e] + clsb[e];
#pragma unroll
    for (int ks = 0; ks < KS; ++ks) v += partial[(ks * G + g) * E + e];
    h[g * E + e] = v;
  }
  __syncthreads();
  ln_rows<E>(h, lng, lnb);
  __syncthreads();
  // mid[m] = gelu(h @ W1 + b1)[m], thread owns m = tid*M1 + r (consecutive -> float2)
  {
    float acc[M1][G];
#pragma unroll
    for (int r = 0; r < M1; ++r)
#pragma unroll
      for (int g = 0; g < G; ++g) acc[r][g] = 0.f;
    for (int j = 0; j < E; j += 8) {
      float wv[M1][8];
#pragma unroll
      for (int ii = 0; ii < 8; ++ii) {
        if constexpr (M1 == 2) {
          float2 w2 = *(const float2*)(W1 + (size_t)(j + ii) * 4 * E + 2 * tid);
          wv[0][ii] = w2.x;
          wv[1][ii] = w2.y;
        } else {
          wv[0][ii] = W1[(size_t)(j + ii) * 4 * E + tid];
        }
      }
#pragma unroll
      for (int g = 0; g < G; ++g) {
        float xv[8];
        LD8(h + g * E + j, xv);
#pragma unroll
        for (int r = 0; r < M1; ++r) fma8(acc[r][g], xv, wv[r]);
      }
    }
#pragma unroll
    for (int r = 0; r < M1; ++r) {
      int m = tid * M1 + r;
      float bias = b1[m];
#pragma unroll
      for (int g = 0; g < G; ++g) mid[g * 4 * E + m] = gelu(acc[r][g] + bias);
    }
  }
  __syncthreads();
  // out = LN(h + mid @ W2 + b2) -> o
  {
    const int e = tid % E, ks = tid / E, m0 = ks * KCH2;
    float acc[G];
#pragma unroll
    for (int g = 0; g < G; ++g) acc[g] = 0.f;
    for (int mc = 0; mc < KCH2; mc += 8) {
      float wv[8];
#pragma unroll
      for (int ii = 0; ii < 8; ++ii) wv[ii] = W2[(size_t)(m0 + mc + ii) * E + e];
#pragma unroll
      for (int g = 0; g < G; ++g) {
        float xv[8];
        LD8(mid + g * 4 * E + m0 + mc, xv);
        fma8(acc[g], xv, wv);
      }
    }
#pragma unroll
    for (int g = 0; g < G; ++g) partial[(ks * G + g) * E + e] = acc[g];
  }
  __syncthreads();
  for (int i = tid; i < G * E; i += NT) {
    int e = i % E, g = i / E;
    float v = b2[e] + h[g * E + e];
#pragma unroll
    for (int ks = 0; ks < KS; ++ks) v += partial[(ks * G + g) * E + e];
    o[g * E + e] = v;
  }
  __syncthreads();
  ln_rows<E>(o, lng, lnb);
  __syncthreads();
}

// ===================== kernel 1: sub path =====================
__global__ __launch_bounds__(NT) void k_sub(P p) {
  __shared__ __align__(16) float X1[8 * G * 64];
  __shared__ __align__(16) float X2[3 * G * 64];
  __shared__ __align__(16) float clsb[64];
  __shared__ __align__(16) float qb[64];
  __shared__ __align__(16) float uL[4 * 64];
  __shared__ __align__(16) float sbL[4];
  __shared__ __align__(16) float att[G * 4 * 9];
  __shared__ __align__(16) float xbar[G * 4 * 64];
  __shared__ __align__(16) float ob[G * 64];
  __shared__ __align__(16) float hb[G * 64];
  __shared__ __align__(16) float mid[G * 256];
  __shared__ __align__(16) float partial[4 * G * 64];
  __shared__ __align__(16) float vec1[G * 64];
  __shared__ __align__(16) float feats[G * 11 * 32];
  const int tid = threadIdx.x, b0 = blockIdx.x * G;

  // stage sub feats: feats[g][f][d]
  const float* subf = p.in[I_SUB];
  for (int i = tid; i < G * 11 * 32; i += NT) {
    int g = i / (11 * 32), r = i % (11 * 32);
    feats[i] = subf[(size_t)(b0 + g) * 352 + r];
  }
  __syncthreads();

  // subfield align: X[f][g][e]
  const float* saW = p.in[I_SAW];
  const float* sab = p.in[I_SAB];
  for (int i = tid; i < 11 * 64; i += NT) {
    int f = i / 64, e = i % 64;
    float bias = sab[f * 64 + e];
    float acc[G];
#pragma unroll
    for (int g = 0; g < G; ++g) acc[g] = bias;
    for (int d = 0; d < 32; d += 8) {
      float wv[8];
#pragma unroll
      for (int ii = 0; ii < 8; ++ii) wv[ii] = saW[(size_t)(f * 32 + d + ii) * 64 + e];
#pragma unroll
      for (int g = 0; g < G; ++g) {
        float xv[8];
        LD8(feats + (g * 11 + f) * 32 + d, xv);
        fma8(acc[g], xv, wv);
      }
    }
#pragma unroll
    for (int g = 0; g < G; ++g) {
      if (f < 8) X1[(f * G + g) * 64 + e] = acc[g];
      else       X2[((f - 8) * G + g) * 64 + e] = acc[g];
    }
  }
  __syncthreads();

  // agg1: tcp.flags (subfields 0..7)
  if (tid < 64) clsb[tid] = p.in[I_SCLS][tid];
  __syncthreads();
  compute_usb<64>(p.in[I_SWQKV], p.in[I_SBQKV], clsb, qb, uL, sbL);
  agg_run<64, 8>(X1, clsb, uL, sbL,
                 p.in[I_SWQKV] + 2 * 64 * 64, p.in[I_SBQKV] + 128,
                 p.in[I_SWO], p.in[I_SBO], p.in[I_SLNG], p.in[I_SLNB],
                 p.in[I_SW1], p.in[I_SB1], p.in[I_SW2], p.in[I_SB2],
                 att, xbar, ob, hb, mid, partial);
  for (int i = tid; i < G * 64; i += NT) vec1[i] = ob[i];
  __syncthreads();

  // agg2: ip.flags (subfields 8..10)
  if (tid < 64) clsb[tid] = p.in[I_SCLS][64 + tid];
  __syncthreads();
  compute_usb<64>(p.in[I_SWQKV] + 192 * 64, p.in[I_SBQKV] + 192, clsb, qb, uL, sbL);
  agg_run<64, 3>(X2, clsb, uL, sbL,
                 p.in[I_SWQKV] + 192 * 64 + 2 * 64 * 64, p.in[I_SBQKV] + 192 + 128,
                 p.in[I_SWO] + 64 * 64, p.in[I_SBO] + 64,
                 p.in[I_SLNG] + 64, p.in[I_SLNB] + 64,
                 p.in[I_SW1] + 64 * 256, p.in[I_SB1] + 256,
                 p.in[I_SW2] + 256 * 64, p.in[I_SB2] + 64,
                 att, xbar, ob, hb, mid, partial);

  // parent_al: [:,0] = tcpf @ paW0 + pab0 ; [:,1] = ipf @ paW1 + pab1
  {
    const int pi = tid >> 7, e = tid & 127;
    const float* paW = p.in[I_PAW];
    float bias = p.in[I_PAB][pi * 128 + e];
    float acc[G];
#pragma unroll
    for (int g = 0; g < G; ++g) acc[g] = bias;
    const float* src = pi ? ob : vec1;
    for (int j = 0; j < 64; j += 8) {
      float wv[8];
#pragma unroll
      for (int ii = 0; ii < 8; ++ii) wv[ii] = paW[(size_t)(pi * 64 + j + ii) * 128 + e];
#pragma unroll
      for (int g = 0; g < G; ++g) {
        float xv[8];
        LD8(src + g * 64 + j, xv);
        fma8(acc[g], xv, wv);
      }
    }
#pragma unroll
    for (int g = 0; g < G; ++g)
      p.parent_al[(size_t)(b0 + g) * 256 + pi * 128 + e] = acc[g];
  }
}

// ===================== kernel 2: parent aggs =====================
template <int T, int F, int F0, int PAR, int AI>
__device__ void parent_body(const P& p, int b0, float* X, float* clsb, float* qb,
                            float* uL, float* sbL, float* att, float* xbar,
                            float* ob, float* hb, float* mid, float* partial,
                            float* feats) {
  const int tid = threadIdx.x;
  const float* leaf = p.in[I_LEAF];
  // stage leaf feats: feats[g][f][d]
  for (int i = tid; i < G * F * 32; i += NT) {
    int g = i / (F * 32), r = i % (F * 32);
    feats[i] = leaf[(size_t)(b0 + g) * 1088 + F0 * 32 + r];
  }
  __syncthreads();
  const float* laW = p.in[I_LAW];
  const float* lab = p.in[I_LAB];
  for (int i = tid; i < F * 128; i += NT) {
    int f = i / 128, e = i % 128;
    float bias = lab[(F0 + f) * 128 + e];
    float acc[G];
#pragma unroll
    for (int g = 0; g < G; ++g) acc[g] = bias;
    for (int d = 0; d < 32; d += 8) {
      float wv[8];
#pragma unroll
      for (int ii = 0; ii < 8; ++ii)
        wv[ii] = laW[(size_t)((F0 + f) * 32 + d + ii) * 128 + e];
#pragma unroll
      for (int g = 0; g < G; ++g) {
        float xv[8];
        LD8(feats + (g * F + f) * 32 + d, xv);
        fma8(acc[g], xv, wv);
      }
    }
#pragma unroll
    for (int g = 0; g < G; ++g) X[(f * G + g) * 128 + e] = acc[g];
  }
  if (PAR >= 0) {
    for (int i = tid; i < G * 128; i += NT) {
      int g = i / 128, e = i % 128;
      X[((T - 1) * G + g) * 128 + e] = p.parent_al[(size_t)(b0 + g) * 256 + PAR * 128 + e];
    }
  }
  if (tid < 128) clsb[tid] = p.in[I_PCLS][AI * 128 + tid];
  __syncthreads();
  compute_usb<128>(p.in[I_PWQKV] + (size_t)AI * 384 * 128, p.in[I_PBQKV] + AI * 384,
                   clsb, qb, uL, sbL);
  agg_run<128, T>(X, clsb, uL, sbL,
                  p.in[I_PWQKV] + (size_t)AI * 384 * 128 + 2 * 128 * 128,
                  p.in[I_PBQKV] + AI * 384 + 256,
                  p.in[I_PWO] + (size_t)AI * 128 * 128, p.in[I_PBO] + AI * 128,
                  p.in[I_PLNG] + AI * 128, p.in[I_PLNB] + AI * 128,
                  p.in[I_PW1] + (size_t)AI * 128 * 512, p.in[I_PB1] + AI * 512,
                  p.in[I_PW2] + (size_t)AI * 512 * 128, p.in[I_PB2] + AI * 128,
                  att, xbar, ob, hb, mid, partial);
  for (int i = tid; i < G * 128; i += NT) {
    int e = i % 128, g = i / 128;
    p.vecs[(size_t)(b0 + g) * 384 + AI * 128 + e] = ob[g * 128 + e];
  }
}

__global__ __launch_bounds__(NT) void k_parent(P p) {
  __shared__ __align__(16) float X[16 * G * 128];
  __shared__ __align__(16) float clsb[128];
  __shared__ __align__(16) float qb[128];
  __shared__ __align__(16) float uL[4 * 128];
  __shared__ __align__(16) float sbL[4];
  __shared__ __align__(16) float att[G * 4 * 17];
  __shared__ __align__(16) float xbar[G * 4 * 128];
  __shared__ __align__(16) float ob[G * 128];
  __shared__ __align__(16) float hb[G * 128];
  __shared__ __align__(16) float mid[G * 512];
  __shared__ __align__(16) float partial[2 * G * 128];
  __shared__ __align__(16) float feats[G * 15 * 32];
  const int b0 = blockIdx.x * G;
  if (blockIdx.y == 0)
    parent_body<8, 8, 0, -1, 0>(p, b0, X, clsb, qb, uL, sbL, att, xbar, ob, hb, mid, partial, feats);
  else if (blockIdx.y == 1)
    parent_body<12, 11, 8, 1, 1>(p, b0, X, clsb, qb, uL, sbL, att, xbar, ob, hb, mid, partial, feats);
  else
    parent_body<16, 15, 19, 0, 2>(p, b0, X, clsb, qb, uL, sbL, att, xbar, ob, hb, mid, partial, feats);
}

// ===================== kernel 3: pkt agg + classifier =====================
__global__ __launch_bounds__(NT) void k_pkt(P p) {
  __shared__ __align__(16) float X[3 * G * 128];
  __shared__ __align__(16) float clsb[128];
  __shared__ __align__(16) float qb[128];
  __shared__ __align__(16) float uL[4 * 128];
  __shared__ __align__(16) float sbL[4];
  __shared__ __align__(16) float att[G * 4 * 4];
  __shared__ __align__(16) float xbar[G * 4 * 128];
  __shared__ __align__(16) float ob[G * 128];
  __shared__ __align__(16) float hb[G * 128];
  __shared__ __align__(16) float mid[G * 512];
  __shared__ __align__(16) float partial[2 * G * 128];
  const int tid = threadIdx.x, b0 = blockIdx.x * G;

  for (int i = tid; i < 3 * G * 128; i += NT) {
    int e = i % 128, g = (i / 128) % G, t = i / (G * 128);
    X[(t * G + g) * 128 + e] = p.vecs[(size_t)(b0 + g) * 384 + t * 128 + e];
  }
  if (tid < 128) clsb[tid] = p.in[I_PCLS][3 * 128 + tid];
  __syncthreads();
  compute_usb<128>(p.in[I_PWQKV] + (size_t)3 * 384 * 128, p.in[I_PBQKV] + 3 * 384,
                   clsb, qb, uL, sbL);
  agg_run<128, 3>(X, clsb, uL, sbL,
                  p.in[I_PWQKV] + (size_t)3 * 384 * 128 + 2 * 128 * 128,
                  p.in[I_PBQKV] + 3 * 384 + 256,
                  p.in[I_PWO] + (size_t)3 * 128 * 128, p.in[I_PBO] + 3 * 128,
                  p.in[I_PLNG] + 3 * 128, p.in[I_PLNB] + 3 * 128,
                  p.in[I_PW1] + (size_t)3 * 128 * 512, p.in[I_PB1] + 3 * 512,
                  p.in[I_PW2] + (size_t)3 * 512 * 128, p.in[I_PB2] + 3 * 128,
                  att, xbar, ob, hb, mid, partial);

  if (tid < G * 2) {
    int g = tid >> 1, c = tid & 1;
    const float* cw = p.in[I_CLFW];
    float acc = p.in[I_CLFB][c];
    for (int j = 0; j < 128; ++j) acc += ob[g * 128 + j] * cw[j * 2 + c];
    p.out[(size_t)(b0 + g) * 2 + c] = acc;
  }
}

extern "C" void kernel_launch(void* const* d_in, const int* in_sizes, int n_in,
                              void* d_out, int out_size, void* d_ws, size_t ws_size,
                              hipStream_t stream) {
  P p;
  for (int i = 0; i < 32; ++i) p.in[i] = (const float*)d_in[i];
  const int B = in_sizes[0] / (34 * 32);
  float* ws = (float*)d_ws;
  p.parent_al = ws;                        // B*256 floats
  p.vecs = ws + (size_t)B * 256;           // B*384 floats
  p.out = (float*)d_out;

  k_sub<<<dim3(B / G), dim3(NT), 0, stream>>>(p);
  k_parent<<<dim3(B / G, 3), dim3(NT), 0, stream>>>(p);
  k_pkt<<<dim3(B / G), dim3(NT), 0, stream>>>(p);
}